// Round 1
// baseline (8147.843 us; speedup 1.0000x reference)
//
#include <hip/hip_runtime.h>
#include <hip/hip_bf16.h>
#include <math.h>

#define BB 256
#define LL 256
#define DD 4
#define HH 1024
#define SS 100
#define OUTD 3
#define X0 768          /* L*OUT */
#define K1 1792         /* 768 + 1024 */
#define K2 2048
#define NG 4096

typedef __attribute__((ext_vector_type(4))) float f32x4;
typedef __attribute__((ext_vector_type(8))) short bf16x8;
typedef __hip_bfloat16 bf16;

__device__ __forceinline__ float sigmoidf_(float x){ return 1.0f/(1.0f + __expf(-x)); }

// ---- 32x32 C-tile per wave, K-major operands A[m][k] (lda) and W[n][k] (ldw) ----
// mfma_f32_16x16x32_bf16: A lane: row=lane%16, k=8*(lane/16)+e ; B lane: col=lane%16, same k
// C/D: col=lane&15, row=(lane>>4)*4+reg (m89-verified)
__device__ __forceinline__ void gemm32x32(const bf16* __restrict__ A, int lda,
                                          const bf16* __restrict__ W, int ldw,
                                          int m0, int wr0, int K,
                                          f32x4 acc[2][2], int lane)
{
  int r  = lane & 15;
  int kq = lane >> 4;
  const bf16* a0 = A + (size_t)(m0 + r)      * lda + kq*8;
  const bf16* a1 = A + (size_t)(m0 + 16 + r) * lda + kq*8;
  const bf16* b0 = W + (size_t)(wr0 + r)      * ldw + kq*8;
  const bf16* b1 = W + (size_t)(wr0 + 16 + r) * ldw + kq*8;
  for (int kk = 0; kk < K; kk += 32) {
    bf16x8 av0 = *(const bf16x8*)(a0 + kk);
    bf16x8 av1 = *(const bf16x8*)(a1 + kk);
    bf16x8 bv0 = *(const bf16x8*)(b0 + kk);
    bf16x8 bv1 = *(const bf16x8*)(b1 + kk);
    acc[0][0] = __builtin_amdgcn_mfma_f32_16x16x32_bf16(av0, bv0, acc[0][0], 0,0,0);
    acc[0][1] = __builtin_amdgcn_mfma_f32_16x16x32_bf16(av0, bv1, acc[0][1], 0,0,0);
    acc[1][0] = __builtin_amdgcn_mfma_f32_16x16x32_bf16(av1, bv0, acc[1][0], 0,0,0);
    acc[1][1] = __builtin_amdgcn_mfma_f32_16x16x32_bf16(av1, bv1, acc[1][1], 0,0,0);
  }
}

// ---- LSTM cell: GEMM over 4 gates (wave==gate) + fused pointwise via LDS exchange ----
template<int K, bool WTANH>
__global__ __launch_bounds__(256) void lstm_cell_kernel(
    const bf16* __restrict__ Acat, const bf16* __restrict__ Wcat,
    const float* __restrict__ bias, float* __restrict__ cst,
    bf16* __restrict__ dstA, int ldA, bf16* __restrict__ dstB, int ldB)
{
  __shared__ float g_lds[4][32][32];
  int tid = threadIdx.x;
  int wave = tid >> 6, lane = tid & 63;
  int m0 = blockIdx.x * 32;
  int n0 = blockIdx.y * 32;              // gate-local col base
  f32x4 acc[2][2] = {};
  gemm32x32(Acat, K, Wcat, K, m0, wave*HH + n0, K, acc, lane);
  int cr = lane & 15, rq = lane >> 4;
  for (int r=0;r<2;r++) for (int c=0;c<2;c++) for (int j=0;j<4;j++)
    g_lds[wave][r*16 + rq*4 + j][c*16 + cr] = acc[r][c][j];
  __syncthreads();
  for (int e = 0; e < 4; e++) {
    int idx = tid + e*256;
    int ml = idx >> 5, nl = idx & 31;
    int m = m0 + ml, n = n0 + nl;
    float gi = g_lds[0][ml][nl] + bias[n];
    float gf = g_lds[1][ml][nl] + bias[HH + n];
    float gg = g_lds[2][ml][nl] + bias[2*HH + n];
    float go = g_lds[3][ml][nl] + bias[3*HH + n];
    float cold = cst[m*HH + n];
    float cn = sigmoidf_(gf)*cold + sigmoidf_(gi)*tanhf(gg);
    float hn = sigmoidf_(go)*tanhf(cn);
    cst[m*HH + n] = cn;
    dstA[(size_t)m*ldA + n] = __float2bfloat16(hn);
    dstB[(size_t)m*ldB + n] = __float2bfloat16(WTANH ? tanhf(hn) : hn);
  }
}

// ---- dec: tanh(h1n) @ Wlin^T + diffusion update, fused output/prev/x-next writes ----
__global__ __launch_bounds__(256) void dec_kernel(
    const bf16* __restrict__ th, const bf16* __restrict__ Wl,
    const float* __restrict__ alphas, const float* __restrict__ betas,
    const float* __restrict__ baralphas, const float* __restrict__ snoise,
    float* __restrict__ prev, float* __restrict__ out,
    bf16* __restrict__ xnext, int t)
{
  int tid = threadIdx.x, wave = tid>>6, lane = tid&63;
  int m0 = blockIdx.x*32;
  int n0 = (blockIdx.y*4 + wave)*32;
  f32x4 acc[2][2] = {};
  gemm32x32(th, HH, Wl, HH, m0, n0, HH, acc, lane);
  int idx = SS - t;
  float a = alphas[idx], ba = baralphas[idx], be = betas[idx];
  float coef = (1.0f - a) / sqrtf(1.0f - ba);
  float isq  = 1.0f / sqrtf(a);
  float nf = (t+1 < SS) ? sqrtf(be) : 0.0f;
  float* outp = out + (size_t)(SS-1-t) * (BB*X0);
  int cr = lane&15, rq = lane>>4;
  for (int r=0;r<2;r++) for (int c=0;c<2;c++) for (int j=0;j<4;j++) {
    int m = m0 + r*16 + rq*4 + j;
    int n = n0 + c*16 + cr;
    float d = acc[r][c][j];
    float p = prev[m*X0 + n];
    float dec = (p - coef*d)*isq + nf*snoise[t*BB + m];
    outp[m*X0 + n] = dec;
    prev[m*X0 + n] = dec;
    xnext[(size_t)m*K1 + n] = __float2bfloat16(dec);
  }
}

// ---- resnet GEMMs (K=1024) with epilogues ----
// EPI 0: relu(C+b)+resid -> bf16 d1
// EPI 1: tanh(C+b) -> bf16, split at n=HH to d1/d2 (h0-init, h1-init)
// EPI 2: tanh(C+b) -> f32, split at n=HH to f1/f2 (c0-init, c1-init)
template<int EPI>
__global__ __launch_bounds__(256) void rgemm_kernel(
    const bf16* __restrict__ A, const bf16* __restrict__ W,
    const float* __restrict__ bias, const float* __restrict__ resid,
    bf16* __restrict__ d1, int ld1, bf16* __restrict__ d2, int ld2,
    float* __restrict__ f1, float* __restrict__ f2)
{
  int tid=threadIdx.x, wave=tid>>6, lane=tid&63;
  int m0 = blockIdx.x*32;
  int n0 = (blockIdx.y*4+wave)*32;
  f32x4 acc[2][2] = {};
  gemm32x32(A, HH, W, HH, m0, n0, HH, acc, lane);
  int cr=lane&15, rq=lane>>4;
  for (int r=0;r<2;r++) for (int c=0;c<2;c++) for (int j=0;j<4;j++) {
    int m = m0 + r*16+rq*4+j, n = n0 + c*16+cr;
    float v = acc[r][c][j] + bias[n];
    if (EPI==0) {
      float h = fmaxf(v,0.f) + resid[m*HH+n];
      d1[(size_t)m*ld1+n] = __float2bfloat16(h);
    } else if (EPI==1) {
      float tv = tanhf(v);
      if (n < HH) d1[(size_t)m*ld1+n] = __float2bfloat16(tv);
      else        d2[(size_t)m*ld2 + (n-HH)] = __float2bfloat16(tv);
    } else {
      float tv = tanhf(v);
      if (n < HH) f1[m*HH+n] = tv;
      else        f2[m*HH + (n-HH)] = tv;
    }
  }
}

// ---- setup kernels ----
__global__ void prep_w0_kernel(const float* __restrict__ Wih0, const float* __restrict__ Whh0,
                               bf16* __restrict__ W0cat){
  int i = blockIdx.x*256 + threadIdx.x;
  if (i >= NG*K1) return;
  int n = i / K1, k = i % K1;
  float v = (k < X0) ? Wih0[n*X0 + k] : Whh0[n*HH + (k - X0)];
  W0cat[i] = __float2bfloat16(v);
}
__global__ void prep_w1_kernel(const float* __restrict__ Wih1, const float* __restrict__ Whh1,
                               bf16* __restrict__ W1cat){
  int i = blockIdx.x*256 + threadIdx.x;
  if (i >= NG*K2) return;
  int n = i / K2, k = i % K2;
  float v = (k < HH) ? Wih1[n*HH + k] : Whh1[n*HH + (k - HH)];
  W1cat[i] = __float2bfloat16(v);
}
__global__ void cvt_kernel(const float* __restrict__ s, bf16* __restrict__ d, int n){
  int i = blockIdx.x*256 + threadIdx.x;
  if (i < n) d[i] = __float2bfloat16(s[i]);
}
__global__ void prep_bias_kernel(const float* bih0, const float* bhh0,
                                 const float* bih1, const float* bhh1,
                                 float* b0, float* b1){
  int i = blockIdx.x*256 + threadIdx.x;
  if (i < NG){ b0[i] = bih0[i] + bhh0[i]; b1[i] = bih1[i] + bhh1[i]; }
}
__global__ void init_x_kernel(const float* __restrict__ z, float* __restrict__ prev,
                              bf16* __restrict__ xcat1, float* __restrict__ out){
  int i = blockIdx.x*256 + threadIdx.x;
  if (i >= BB*X0) return;
  int m = i / X0, col = i % X0;
  int l = col / OUTD, d = col % OUTD;
  float v = z[(size_t)(m*LL + l)*DD + d];
  prev[i] = v;
  out[(size_t)(SS-1)*BB*X0 + i] = v;
  xcat1[(size_t)m*K1 + col] = __float2bfloat16(v);
}
__global__ void r1_kernel(const float* __restrict__ n0,
    const float* __restrict__ A1a, const float* __restrict__ b1a,
    const float* __restrict__ A1b, const float* __restrict__ b1b,
    float* __restrict__ h1fa, bf16* __restrict__ h1ba,
    float* __restrict__ h1fb, bf16* __restrict__ h1bb){
  int gid = blockIdx.x*256 + threadIdx.x;
  if (gid >= BB*2*HH) return;
  int m = gid >> 11;
  int col = gid & 2047;
  const float* A1; const float* b1; float* hf; bf16* hb; int c;
  if (col < HH){ A1=A1a; b1=b1a; hf=h1fa; hb=h1ba; c=col; }
  else         { A1=A1b; b1=b1b; hf=h1fb; hb=h1bb; c=col-HH; }
  float v = b1[c];
  for (int d=0; d<DD; d++) v += n0[m*DD + d] * A1[c*DD + d];
  v = fmaxf(v, 0.f);
  hf[m*HH + c] = v;
  hb[m*HH + c] = __float2bfloat16(v);
}

static inline size_t alup(size_t x){ return (x + 255) & ~(size_t)255; }

extern "C" void kernel_launch(void* const* d_in, const int* in_sizes, int n_in,
                              void* d_out, int out_size, void* d_ws, size_t ws_size,
                              hipStream_t stream) {
  const float* z      = (const float*)d_in[4];
  const float* n0     = (const float*)d_in[5];
  const float* snoise = (const float*)d_in[6];
  const float* alphas = (const float*)d_in[7];
  const float* betas  = (const float*)d_in[8];
  const float* barals = (const float*)d_in[9];
  const float* A1a = (const float*)d_in[10]; const float* b1a = (const float*)d_in[11];
  const float* A2a = (const float*)d_in[12]; const float* b2a = (const float*)d_in[13];
  const float* A3a = (const float*)d_in[14]; const float* b3a = (const float*)d_in[15];
  const float* A1b = (const float*)d_in[16]; const float* b1b = (const float*)d_in[17];
  const float* A2b = (const float*)d_in[18]; const float* b2b = (const float*)d_in[19];
  const float* A3b = (const float*)d_in[20]; const float* b3b = (const float*)d_in[21];
  const float* Wih0 = (const float*)d_in[22]; const float* Whh0 = (const float*)d_in[23];
  const float* bih0 = (const float*)d_in[24]; const float* bhh0 = (const float*)d_in[25];
  const float* Wih1 = (const float*)d_in[26]; const float* Whh1 = (const float*)d_in[27];
  const float* bih1 = (const float*)d_in[28]; const float* bhh1 = (const float*)d_in[29];
  const float* Wlin = (const float*)d_in[30];
  float* out = (float*)d_out;

  // ---- workspace carve-up ----
  char* p = (char*)d_ws;
  size_t off = 0;
  auto take = [&](size_t bytes)->char*{ char* r = p + off; off = alup(off + bytes); return r; };
  bf16* W0cat = (bf16*)take((size_t)NG*K1*2);
  bf16* W1cat = (bf16*)take((size_t)NG*K2*2);
  bf16* WlinB = (bf16*)take((size_t)X0*HH*2);
  bf16* A2aB  = (bf16*)take((size_t)HH*HH*2);
  bf16* A2bB  = (bf16*)take((size_t)HH*HH*2);
  bf16* A3aB  = (bf16*)take((size_t)2*HH*HH*2);
  bf16* A3bB  = (bf16*)take((size_t)2*HH*HH*2);
  float* bias0 = (float*)take(NG*4);
  float* bias1 = (float*)take(NG*4);
  bf16* xcat0 = (bf16*)take((size_t)BB*K1*2);
  bf16* xcat1 = (bf16*)take((size_t)BB*K1*2);
  bf16* x2_0  = (bf16*)take((size_t)BB*K2*2);
  bf16* x2_1  = (bf16*)take((size_t)BB*K2*2);
  bf16* th    = (bf16*)take((size_t)BB*HH*2);
  float* c0   = (float*)take((size_t)BB*HH*4);
  float* c1   = (float*)take((size_t)BB*HH*4);
  float* prev = (float*)take((size_t)BB*X0*4);
  float* h1fa = (float*)take((size_t)BB*HH*4);
  float* h1fb = (float*)take((size_t)BB*HH*4);
  bf16* h1ba  = (bf16*)take((size_t)BB*HH*2);
  bf16* h1bb  = (bf16*)take((size_t)BB*HH*2);
  bf16* h2ba  = (bf16*)take((size_t)BB*HH*2);
  bf16* h2bb  = (bf16*)take((size_t)BB*HH*2);
  (void)ws_size; (void)in_sizes; (void)n_in; (void)out_size;

  // ---- setup ----
  prep_w0_kernel<<<(NG*K1+255)/256, 256, 0, stream>>>(Wih0, Whh0, W0cat);
  prep_w1_kernel<<<(NG*K2+255)/256, 256, 0, stream>>>(Wih1, Whh1, W1cat);
  cvt_kernel<<<(X0*HH+255)/256, 256, 0, stream>>>(Wlin, WlinB, X0*HH);
  cvt_kernel<<<(HH*HH+255)/256, 256, 0, stream>>>(A2a, A2aB, HH*HH);
  cvt_kernel<<<(HH*HH+255)/256, 256, 0, stream>>>(A2b, A2bB, HH*HH);
  cvt_kernel<<<(2*HH*HH+255)/256, 256, 0, stream>>>(A3a, A3aB, 2*HH*HH);
  cvt_kernel<<<(2*HH*HH+255)/256, 256, 0, stream>>>(A3b, A3bB, 2*HH*HH);
  prep_bias_kernel<<<(NG+255)/256, 256, 0, stream>>>(bih0, bhh0, bih1, bhh1, bias0, bias1);
  init_x_kernel<<<(BB*X0+255)/256, 256, 0, stream>>>(z, prev, xcat1, out);
  r1_kernel<<<(BB*2*HH+255)/256, 256, 0, stream>>>(n0, A1a, b1a, A1b, b1b, h1fa, h1ba, h1fb, h1bb);
  // h2 = relu(h1@A2^T + b2) + h1
  rgemm_kernel<0><<<dim3(8,8), 256, 0, stream>>>(h1ba, A2aB, b2a, h1fa, h2ba, HH, nullptr, 0, nullptr, nullptr);
  rgemm_kernel<0><<<dim3(8,8), 256, 0, stream>>>(h1bb, A2bB, b2b, h1fb, h2bb, HH, nullptr, 0, nullptr, nullptr);
  // out_a -> h0 (xcat1 cols 768:), h1 (x2_1 cols 1024:) ; out_b -> c0, c1
  rgemm_kernel<1><<<dim3(8,16), 256, 0, stream>>>(h2ba, A3aB, b3a, nullptr, xcat1 + X0, K1, x2_1 + HH, K2, nullptr, nullptr);
  rgemm_kernel<2><<<dim3(8,16), 256, 0, stream>>>(h2bb, A3bB, b3b, nullptr, nullptr, 0, nullptr, 0, c0, c1);

  // ---- 99 diffusion steps ----
  for (int t = 1; t < SS; t++) {
    bf16* xc  = (t & 1) ? xcat1 : xcat0;   // read [x|h0]
    bf16* xn  = (t & 1) ? xcat0 : xcat1;   // next step's [x|h0]
    bf16* x2c = (t & 1) ? x2_1 : x2_0;     // read [h0n|h1]
    bf16* x2n = (t & 1) ? x2_0 : x2_1;
    // cell0: writes h0n -> x2c[:,0:1024] (for cell1 now) and xn[:,768:] (for next step)
    lstm_cell_kernel<K1,false><<<dim3(8,32), 256, 0, stream>>>(
        xc, W0cat, bias0, c0, x2c, K2, xn + X0, K1);
    // cell1: writes h1n -> x2n[:,1024:] (next step) and tanh(h1n) -> th
    lstm_cell_kernel<K2,true><<<dim3(8,32), 256, 0, stream>>>(
        x2c, W1cat, bias1, c1, x2n + HH, K2, th, HH);
    // dec: out frame 99-t, prev update, bf16 x -> xn[:,0:768]
    dec_kernel<<<dim3(8,6), 256, 0, stream>>>(
        th, WlinB, alphas, betas, barals, snoise, prev, out, xn, t);
  }
}

// Round 2
// 4049.028 us; speedup vs baseline: 2.0123x; 2.0123x over previous
//
#include <hip/hip_runtime.h>
#include <hip/hip_bf16.h>
#include <math.h>

#define BB 256
#define LL 256
#define DD 4
#define HH 1024
#define SS 100
#define OUTD 3
#define X0 768          /* L*OUT */
#define K1 1792         /* 768 + 1024 */
#define K2 2048
#define NG 4096
#define BKB 128         /* bytes per row per K-chunk (64 bf16) */

typedef __attribute__((ext_vector_type(4))) float f32x4;
typedef __attribute__((ext_vector_type(8))) short bf16x8;
typedef __hip_bfloat16 bf16;

__device__ __forceinline__ float sigmoidf_(float x){ return 1.0f/(1.0f + __expf(-x)); }

__device__ __forceinline__ void gll16(const void* g, void* l){
  __builtin_amdgcn_global_load_lds((const __attribute__((address_space(1))) unsigned int*)g,
                                   (__attribute__((address_space(3))) unsigned int*)l, 16, 0, 0);
}

// =====================================================================
// LSTM cell v2: block = 64 rows x (4 gates x 32 cols). grid (4,32), 512 thr.
// LDS: double-buffered A tile 64x64 bf16 (8KB) + W tile 128x64 (16KB).
// Staged via global_load_lds w/ pre-swizzled source; XOR-swizzled ds_read_b128.
// 2-phase pipeline, counted vmcnt(3). Fused gate pointwise via LDS exchange.
// =====================================================================
template<int K, bool WTANH>
__global__ __launch_bounds__(512) void cell_v2(
    const bf16* __restrict__ Acat, const bf16* __restrict__ Wcat,
    const float* __restrict__ bias, float* __restrict__ cst,
    bf16* __restrict__ dstA, int ldA, bf16* __restrict__ dstB, int ldB)
{
  __shared__ __align__(16) char smem[49152];   // buf0 @0 (A 8K, W 16K), buf1 @24576
  const int tid  = threadIdx.x;
  const int wave = tid >> 6, lane = tid & 63;
  const int m0 = blockIdx.x * 64;
  const int n0 = blockIdx.y * 32;              // gate-local col base
  const int wm = wave >> 2, wn = wave & 3;     // wn = gate index
  const int l7 = lane & 7, l3 = lane >> 3;
  const int swz = 16 * (l7 ^ l3);              // source pre-swizzle (involution)

  // ---- staging setup: 3 chunks of 1024B per wave (8 A-chunks, 16 W-chunks) ----
  const char* src[3];
  char* dstL[2][3];
  #pragma unroll
  for (int i = 0; i < 3; i++){
    int c = wave*3 + i;
    const bf16* base; size_t roff; int ldsoff;
    if (c < 8){                       // A chunk: rows c*8 + l3
      int row = c*8 + l3;
      base = Acat; roff = (size_t)(m0 + row) * K; ldsoff = c*1024;
    } else {                          // W chunk: wrows (c-8)*8 + l3 of 128 (gate-major)
      int wr = (c-8)*8 + l3;
      int g = wr >> 5, j = wr & 31;
      base = Wcat; roff = (size_t)(g*HH + n0 + j) * K; ldsoff = 8192 + (c-8)*1024;
    }
    src[i] = (const char*)(base + roff) + swz;
    dstL[0][i] = smem + ldsoff;
    dstL[1][i] = smem + 24576 + ldsoff;
  }

  // ---- fragment read offsets (swizzled) ----
  const int lr = lane & 15, kq = lane >> 4;
  const int rsw = (lr & 7) << 4;
  int offA[2][2], offB[2][2];
  #pragma unroll
  for (int mt = 0; mt < 2; mt++)
    #pragma unroll
    for (int s = 0; s < 2; s++){
      int row = wm*32 + mt*16 + lr;
      offA[mt][s] = row*BKB + ((s*64 + kq*16) ^ rsw);
    }
  #pragma unroll
  for (int nt = 0; nt < 2; nt++)
    #pragma unroll
    for (int s = 0; s < 2; s++){
      int wr = wn*32 + nt*16 + lr;
      offB[nt][s] = 8192 + wr*BKB + ((s*64 + kq*16) ^ rsw);
    }

  f32x4 acc[2][2] = {};
  constexpr int NT = K / 64;

  // prologue: stage chunk 0 into buf0
  #pragma unroll
  for (int i = 0; i < 3; i++) gll16(src[i], dstL[0][i]);

  for (int t = 0; t < NT; ++t){
    const int b = t & 1;
    if (t + 1 < NT){
      #pragma unroll
      for (int i = 0; i < 3; i++) gll16(src[i] + (size_t)(t+1)*BKB, dstL[(t+1)&1][i]);
      asm volatile("s_waitcnt vmcnt(3)" ::: "memory");
    } else {
      asm volatile("s_waitcnt vmcnt(0)" ::: "memory");
    }
    __builtin_amdgcn_s_barrier();
    __builtin_amdgcn_sched_barrier(0);

    const char* cbase = smem + b*24576;
    bf16x8 Af[2][2], Bf[2][2];
    #pragma unroll
    for (int mt = 0; mt < 2; mt++)
      #pragma unroll
      for (int s = 0; s < 2; s++) Af[mt][s] = *(const bf16x8*)(cbase + offA[mt][s]);
    #pragma unroll
    for (int nt = 0; nt < 2; nt++)
      #pragma unroll
      for (int s = 0; s < 2; s++) Bf[nt][s] = *(const bf16x8*)(cbase + offB[nt][s]);
    #pragma unroll
    for (int s = 0; s < 2; s++)
      #pragma unroll
      for (int mt = 0; mt < 2; mt++)
        #pragma unroll
        for (int nt = 0; nt < 2; nt++)
          acc[mt][nt] = __builtin_amdgcn_mfma_f32_16x16x32_bf16(Af[mt][s], Bf[nt][s], acc[mt][nt], 0,0,0);

    __builtin_amdgcn_sched_barrier(0);
    __builtin_amdgcn_s_barrier();
  }

  // ---- epilogue: gates -> LDS exchange -> fused pointwise ----
  float* g_lds = (float*)smem;   // 2*4*32*32*4 = 32KB, overwrite staging (all reads done)
  const int cr = lane & 15, rq = lane >> 4;
  #pragma unroll
  for (int mt = 0; mt < 2; mt++)
    #pragma unroll
    for (int nt = 0; nt < 2; nt++)
      #pragma unroll
      for (int j = 0; j < 4; j++){
        int r = mt*16 + rq*4 + j;
        int cc = nt*16 + cr;
        g_lds[((wm*4 + wn)*32 + r)*32 + cc] = acc[mt][nt][j];
      }
  __syncthreads();
  #pragma unroll
  for (int e = 0; e < 4; e++){
    int idx = tid + e*512;            // 0..2047 over 64 rows x 32 cols
    int ml = idx >> 5, nl = idx & 31;
    int w2 = ml >> 5, r = ml & 31;
    int m = m0 + ml, n = n0 + nl;
    float gi = g_lds[((w2*4+0)*32 + r)*32 + nl] + bias[n];
    float gf = g_lds[((w2*4+1)*32 + r)*32 + nl] + bias[HH + n];
    float gg = g_lds[((w2*4+2)*32 + r)*32 + nl] + bias[2*HH + n];
    float go = g_lds[((w2*4+3)*32 + r)*32 + nl] + bias[3*HH + n];
    float cold = cst[m*HH + n];
    float cn = sigmoidf_(gf)*cold + sigmoidf_(gi)*tanhf(gg);
    float hn = sigmoidf_(go)*tanhf(cn);
    cst[m*HH + n] = cn;
    dstA[(size_t)m*ldA + n] = __float2bfloat16(hn);
    dstB[(size_t)m*ldB + n] = __float2bfloat16(WTANH ? tanhf(hn) : hn);
  }
}

// =====================================================================
// dec v2: 64x64 tile, grid (4,12), 512 thr (8 waves, 32x16/wave), K=1024.
// =====================================================================
__global__ __launch_bounds__(512) void dec_v2(
    const bf16* __restrict__ th, const bf16* __restrict__ Wl,
    const float* __restrict__ alphas, const float* __restrict__ betas,
    const float* __restrict__ baralphas, const float* __restrict__ snoise,
    float* __restrict__ prev, float* __restrict__ out,
    bf16* __restrict__ xnext, int t)
{
  __shared__ __align__(16) char smem[32768];   // buf: A 8K @0, W 8K @8192; buf1 @16384
  const int tid  = threadIdx.x;
  const int wave = tid >> 6, lane = tid & 63;
  const int m0 = blockIdx.x * 64;
  const int n0 = blockIdx.y * 64;
  const int wm = wave >> 2, wn = wave & 3;
  const int l7 = lane & 7, l3 = lane >> 3;
  const int swz = 16 * (l7 ^ l3);

  const char* src[2];
  char* dstL[2][2];
  #pragma unroll
  for (int i = 0; i < 2; i++){
    int c = wave*2 + i;
    const bf16* base; size_t roff; int ldsoff;
    if (c < 8){ int row = c*8 + l3; base = th; roff = (size_t)(m0 + row)*HH; ldsoff = c*1024; }
    else { int wr = (c-8)*8 + l3;  base = Wl; roff = (size_t)(n0 + wr)*HH; ldsoff = 8192 + (c-8)*1024; }
    src[i] = (const char*)(base + roff) + swz;
    dstL[0][i] = smem + ldsoff;
    dstL[1][i] = smem + 16384 + ldsoff;
  }

  const int lr = lane & 15, kq = lane >> 4;
  const int rsw = (lr & 7) << 4;
  int offA[2][2], offB[2];
  #pragma unroll
  for (int mt = 0; mt < 2; mt++)
    #pragma unroll
    for (int s = 0; s < 2; s++){
      int row = wm*32 + mt*16 + lr;
      offA[mt][s] = row*BKB + ((s*64 + kq*16) ^ rsw);
    }
  #pragma unroll
  for (int s = 0; s < 2; s++){
    int wr = wn*16 + lr;
    offB[s] = 8192 + wr*BKB + ((s*64 + kq*16) ^ rsw);
  }

  f32x4 acc[2] = {};
  constexpr int NT = HH / 64;
  #pragma unroll
  for (int i = 0; i < 2; i++) gll16(src[i], dstL[0][i]);

  for (int tt = 0; tt < NT; ++tt){
    const int b = tt & 1;
    if (tt + 1 < NT){
      #pragma unroll
      for (int i = 0; i < 2; i++) gll16(src[i] + (size_t)(tt+1)*BKB, dstL[(tt+1)&1][i]);
      asm volatile("s_waitcnt vmcnt(2)" ::: "memory");
    } else {
      asm volatile("s_waitcnt vmcnt(0)" ::: "memory");
    }
    __builtin_amdgcn_s_barrier();
    __builtin_amdgcn_sched_barrier(0);

    const char* cbase = smem + b*16384;
    bf16x8 Af[2][2], Bf[2];
    #pragma unroll
    for (int mt = 0; mt < 2; mt++)
      #pragma unroll
      for (int s = 0; s < 2; s++) Af[mt][s] = *(const bf16x8*)(cbase + offA[mt][s]);
    #pragma unroll
    for (int s = 0; s < 2; s++) Bf[s] = *(const bf16x8*)(cbase + offB[s]);
    #pragma unroll
    for (int s = 0; s < 2; s++)
      #pragma unroll
      for (int mt = 0; mt < 2; mt++)
        acc[mt] = __builtin_amdgcn_mfma_f32_16x16x32_bf16(Af[mt][s], Bf[s], acc[mt], 0,0,0);

    __builtin_amdgcn_sched_barrier(0);
    __builtin_amdgcn_s_barrier();
  }

  const int idxs = SS - t;
  float a = alphas[idxs], ba = baralphas[idxs], be = betas[idxs];
  float coef = (1.0f - a) / sqrtf(1.0f - ba);
  float isq  = 1.0f / sqrtf(a);
  float nf = (t+1 < SS) ? sqrtf(be) : 0.0f;
  float* outp = out + (size_t)(SS-1-t) * (BB*X0);
  const int cr = lane & 15, rq = lane >> 4;
  #pragma unroll
  for (int mt = 0; mt < 2; mt++)
    #pragma unroll
    for (int j = 0; j < 4; j++){
      int m = m0 + wm*32 + mt*16 + rq*4 + j;
      int n = n0 + wn*16 + cr;
      float d = acc[mt][j];
      float p = prev[m*X0 + n];
      float dec = (p - coef*d)*isq + nf*snoise[t*BB + m];
      outp[m*X0 + n] = dec;
      prev[m*X0 + n] = dec;
      xnext[(size_t)m*K1 + n] = __float2bfloat16(dec);
    }
}

// =====================================================================
// setup-phase helpers (run once; round-0 structure kept)
// =====================================================================
__device__ __forceinline__ void gemm32x32(const bf16* __restrict__ A, int lda,
                                          const bf16* __restrict__ W, int ldw,
                                          int m0, int wr0, int K,
                                          f32x4 acc[2][2], int lane)
{
  int r  = lane & 15;
  int kq = lane >> 4;
  const bf16* a0 = A + (size_t)(m0 + r)      * lda + kq*8;
  const bf16* a1 = A + (size_t)(m0 + 16 + r) * lda + kq*8;
  const bf16* b0 = W + (size_t)(wr0 + r)      * ldw + kq*8;
  const bf16* b1 = W + (size_t)(wr0 + 16 + r) * ldw + kq*8;
  for (int kk = 0; kk < K; kk += 32) {
    bf16x8 av0 = *(const bf16x8*)(a0 + kk);
    bf16x8 av1 = *(const bf16x8*)(a1 + kk);
    bf16x8 bv0 = *(const bf16x8*)(b0 + kk);
    bf16x8 bv1 = *(const bf16x8*)(b1 + kk);
    acc[0][0] = __builtin_amdgcn_mfma_f32_16x16x32_bf16(av0, bv0, acc[0][0], 0,0,0);
    acc[0][1] = __builtin_amdgcn_mfma_f32_16x16x32_bf16(av0, bv1, acc[0][1], 0,0,0);
    acc[1][0] = __builtin_amdgcn_mfma_f32_16x16x32_bf16(av1, bv0, acc[1][0], 0,0,0);
    acc[1][1] = __builtin_amdgcn_mfma_f32_16x16x32_bf16(av1, bv1, acc[1][1], 0,0,0);
  }
}

template<int EPI>
__global__ __launch_bounds__(256) void rgemm_kernel(
    const bf16* __restrict__ A, const bf16* __restrict__ W,
    const float* __restrict__ bias, const float* __restrict__ resid,
    bf16* __restrict__ d1, int ld1, bf16* __restrict__ d2, int ld2,
    float* __restrict__ f1, float* __restrict__ f2)
{
  int tid=threadIdx.x, wave=tid>>6, lane=tid&63;
  int m0 = blockIdx.x*32;
  int n0 = (blockIdx.y*4+wave)*32;
  f32x4 acc[2][2] = {};
  gemm32x32(A, HH, W, HH, m0, n0, HH, acc, lane);
  int cr=lane&15, rq=lane>>4;
  for (int r=0;r<2;r++) for (int c=0;c<2;c++) for (int j=0;j<4;j++) {
    int m = m0 + r*16+rq*4+j, n = n0 + c*16+cr;
    float v = acc[r][c][j] + bias[n];
    if (EPI==0) {
      float h = fmaxf(v,0.f) + resid[m*HH+n];
      d1[(size_t)m*ld1+n] = __float2bfloat16(h);
    } else if (EPI==1) {
      float tv = tanhf(v);
      if (n < HH) d1[(size_t)m*ld1+n] = __float2bfloat16(tv);
      else        d2[(size_t)m*ld2 + (n-HH)] = __float2bfloat16(tv);
    } else {
      float tv = tanhf(v);
      if (n < HH) f1[m*HH+n] = tv;
      else        f2[m*HH + (n-HH)] = tv;
    }
  }
}

__global__ void prep_w0_kernel(const float* __restrict__ Wih0, const float* __restrict__ Whh0,
                               bf16* __restrict__ W0cat){
  int i = blockIdx.x*256 + threadIdx.x;
  if (i >= NG*K1) return;
  int n = i / K1, k = i % K1;
  float v = (k < X0) ? Wih0[n*X0 + k] : Whh0[n*HH + (k - X0)];
  W0cat[i] = __float2bfloat16(v);
}
__global__ void prep_w1_kernel(const float* __restrict__ Wih1, const float* __restrict__ Whh1,
                               bf16* __restrict__ W1cat){
  int i = blockIdx.x*256 + threadIdx.x;
  if (i >= NG*K2) return;
  int n = i / K2, k = i % K2;
  float v = (k < HH) ? Wih1[n*HH + k] : Whh1[n*HH + (k - HH)];
  W1cat[i] = __float2bfloat16(v);
}
__global__ void cvt_kernel(const float* __restrict__ s, bf16* __restrict__ d, int n){
  int i = blockIdx.x*256 + threadIdx.x;
  if (i < n) d[i] = __float2bfloat16(s[i]);
}
__global__ void prep_bias_kernel(const float* bih0, const float* bhh0,
                                 const float* bih1, const float* bhh1,
                                 float* b0, float* b1){
  int i = blockIdx.x*256 + threadIdx.x;
  if (i < NG){ b0[i] = bih0[i] + bhh0[i]; b1[i] = bih1[i] + bhh1[i]; }
}
__global__ void init_x_kernel(const float* __restrict__ z, float* __restrict__ prev,
                              bf16* __restrict__ xcat1, float* __restrict__ out){
  int i = blockIdx.x*256 + threadIdx.x;
  if (i >= BB*X0) return;
  int m = i / X0, col = i % X0;
  int l = col / OUTD, d = col % OUTD;
  float v = z[(size_t)(m*LL + l)*DD + d];
  prev[i] = v;
  out[(size_t)(SS-1)*BB*X0 + i] = v;
  xcat1[(size_t)m*K1 + col] = __float2bfloat16(v);
}
__global__ void r1_kernel(const float* __restrict__ n0,
    const float* __restrict__ A1a, const float* __restrict__ b1a,
    const float* __restrict__ A1b, const float* __restrict__ b1b,
    float* __restrict__ h1fa, bf16* __restrict__ h1ba,
    float* __restrict__ h1fb, bf16* __restrict__ h1bb){
  int gid = blockIdx.x*256 + threadIdx.x;
  if (gid >= BB*2*HH) return;
  int m = gid >> 11;
  int col = gid & 2047;
  const float* A1; const float* b1; float* hf; bf16* hb; int c;
  if (col < HH){ A1=A1a; b1=b1a; hf=h1fa; hb=h1ba; c=col; }
  else         { A1=A1b; b1=b1b; hf=h1fb; hb=h1bb; c=col-HH; }
  float v = b1[c];
  for (int d=0; d<DD; d++) v += n0[m*DD + d] * A1[c*DD + d];
  v = fmaxf(v, 0.f);
  hf[m*HH + c] = v;
  hb[m*HH + c] = __float2bfloat16(v);
}

static inline size_t alup(size_t x){ return (x + 255) & ~(size_t)255; }

extern "C" void kernel_launch(void* const* d_in, const int* in_sizes, int n_in,
                              void* d_out, int out_size, void* d_ws, size_t ws_size,
                              hipStream_t stream) {
  const float* z      = (const float*)d_in[4];
  const float* n0     = (const float*)d_in[5];
  const float* snoise = (const float*)d_in[6];
  const float* alphas = (const float*)d_in[7];
  const float* betas  = (const float*)d_in[8];
  const float* barals = (const float*)d_in[9];
  const float* A1a = (const float*)d_in[10]; const float* b1a = (const float*)d_in[11];
  const float* A2a = (const float*)d_in[12]; const float* b2a = (const float*)d_in[13];
  const float* A3a = (const float*)d_in[14]; const float* b3a = (const float*)d_in[15];
  const float* A1b = (const float*)d_in[16]; const float* b1b = (const float*)d_in[17];
  const float* A2b = (const float*)d_in[18]; const float* b2b = (const float*)d_in[19];
  const float* A3b = (const float*)d_in[20]; const float* b3b = (const float*)d_in[21];
  const float* Wih0 = (const float*)d_in[22]; const float* Whh0 = (const float*)d_in[23];
  const float* bih0 = (const float*)d_in[24]; const float* bhh0 = (const float*)d_in[25];
  const float* Wih1 = (const float*)d_in[26]; const float* Whh1 = (const float*)d_in[27];
  const float* bih1 = (const float*)d_in[28]; const float* bhh1 = (const float*)d_in[29];
  const float* Wlin = (const float*)d_in[30];
  float* out = (float*)d_out;

  char* p = (char*)d_ws;
  size_t off = 0;
  auto take = [&](size_t bytes)->char*{ char* r = p + off; off = alup(off + bytes); return r; };
  bf16* W0cat = (bf16*)take((size_t)NG*K1*2);
  bf16* W1cat = (bf16*)take((size_t)NG*K2*2);
  bf16* WlinB = (bf16*)take((size_t)X0*HH*2);
  bf16* A2aB  = (bf16*)take((size_t)HH*HH*2);
  bf16* A2bB  = (bf16*)take((size_t)HH*HH*2);
  bf16* A3aB  = (bf16*)take((size_t)2*HH*HH*2);
  bf16* A3bB  = (bf16*)take((size_t)2*HH*HH*2);
  float* bias0 = (float*)take(NG*4);
  float* bias1 = (float*)take(NG*4);
  bf16* xcat0 = (bf16*)take((size_t)BB*K1*2);
  bf16* xcat1 = (bf16*)take((size_t)BB*K1*2);
  bf16* x2_0  = (bf16*)take((size_t)BB*K2*2);
  bf16* x2_1  = (bf16*)take((size_t)BB*K2*2);
  bf16* th    = (bf16*)take((size_t)BB*HH*2);
  float* c0   = (float*)take((size_t)BB*HH*4);
  float* c1   = (float*)take((size_t)BB*HH*4);
  float* prev = (float*)take((size_t)BB*X0*4);
  float* h1fa = (float*)take((size_t)BB*HH*4);
  float* h1fb = (float*)take((size_t)BB*HH*4);
  bf16* h1ba  = (bf16*)take((size_t)BB*HH*2);
  bf16* h1bb  = (bf16*)take((size_t)BB*HH*2);
  bf16* h2ba  = (bf16*)take((size_t)BB*HH*2);
  bf16* h2bb  = (bf16*)take((size_t)BB*HH*2);
  (void)ws_size; (void)in_sizes; (void)n_in; (void)out_size;

  prep_w0_kernel<<<(NG*K1+255)/256, 256, 0, stream>>>(Wih0, Whh0, W0cat);
  prep_w1_kernel<<<(NG*K2+255)/256, 256, 0, stream>>>(Wih1, Whh1, W1cat);
  cvt_kernel<<<(X0*HH+255)/256, 256, 0, stream>>>(Wlin, WlinB, X0*HH);
  cvt_kernel<<<(HH*HH+255)/256, 256, 0, stream>>>(A2a, A2aB, HH*HH);
  cvt_kernel<<<(HH*HH+255)/256, 256, 0, stream>>>(A2b, A2bB, HH*HH);
  cvt_kernel<<<(2*HH*HH+255)/256, 256, 0, stream>>>(A3a, A3aB, 2*HH*HH);
  cvt_kernel<<<(2*HH*HH+255)/256, 256, 0, stream>>>(A3b, A3bB, 2*HH*HH);
  prep_bias_kernel<<<(NG+255)/256, 256, 0, stream>>>(bih0, bhh0, bih1, bhh1, bias0, bias1);
  init_x_kernel<<<(BB*X0+255)/256, 256, 0, stream>>>(z, prev, xcat1, out);
  r1_kernel<<<(BB*2*HH+255)/256, 256, 0, stream>>>(n0, A1a, b1a, A1b, b1b, h1fa, h1ba, h1fb, h1bb);
  rgemm_kernel<0><<<dim3(8,8), 256, 0, stream>>>(h1ba, A2aB, b2a, h1fa, h2ba, HH, nullptr, 0, nullptr, nullptr);
  rgemm_kernel<0><<<dim3(8,8), 256, 0, stream>>>(h1bb, A2bB, b2b, h1fb, h2bb, HH, nullptr, 0, nullptr, nullptr);
  rgemm_kernel<1><<<dim3(8,16), 256, 0, stream>>>(h2ba, A3aB, b3a, nullptr, xcat1 + X0, K1, x2_1 + HH, K2, nullptr, nullptr);
  rgemm_kernel<2><<<dim3(8,16), 256, 0, stream>>>(h2bb, A3bB, b3b, nullptr, nullptr, 0, nullptr, 0, c0, c1);

  for (int t = 1; t < SS; t++) {
    bf16* xc  = (t & 1) ? xcat1 : xcat0;
    bf16* xn  = (t & 1) ? xcat0 : xcat1;
    bf16* x2c = (t & 1) ? x2_1 : x2_0;
    bf16* x2n = (t & 1) ? x2_0 : x2_1;
    cell_v2<K1,false><<<dim3(4,32), 512, 0, stream>>>(
        xc, W0cat, bias0, c0, x2c, K2, xn + X0, K1);
    cell_v2<K2,true><<<dim3(4,32), 512, 0, stream>>>(
        x2c, W1cat, bias1, c1, x2n + HH, K2, th, HH);
    dec_v2<<<dim3(4,12), 512, 0, stream>>>(
        th, WlinB, alphas, betas, barals, snoise, prev, out, xn, t);
  }
}